// Round 1
// baseline (112.267 us; speedup 1.0000x reference)
//
#include <hip/hip_runtime.h>
#include <hip/hip_bf16.h>
#include <cstdint>

#define BATCH 8192
#define DIM   128
#define MARGIN 1.0f

typedef __attribute__((ext_vector_type(8))) short short8;
typedef __attribute__((ext_vector_type(4))) float f32x4;

// ---------------------------------------------------------------------------
// Kernel 1: convert fp32 -> bf16, compute per-row squared norms (fp32-exact),
// init hp2 (max-accum, 0) and hn2 (min-accum, +inf). One wave per row.
// ---------------------------------------------------------------------------
__global__ __launch_bounds__(64) void bhtl_prep(
    const float* __restrict__ emb,
    __hip_bfloat16* __restrict__ Ebf,
    float* __restrict__ sq,
    unsigned* __restrict__ hp2,
    unsigned* __restrict__ hn2)
{
    const int row = blockIdx.x;
    const int l   = threadIdx.x;                 // 0..63
    const float2 e = ((const float2*)(emb + row * DIM))[l];
    __hip_bfloat162 h2;
    h2.x = __float2bfloat16(e.x);
    h2.y = __float2bfloat16(e.y);
    ((__hip_bfloat162*)(Ebf + row * DIM))[l] = h2;
    float s = e.x * e.x + e.y * e.y;
    #pragma unroll
    for (int d = 1; d < 64; d <<= 1) s += __shfl_xor(s, d, 64);
    if (l == 0) {
        sq[row]  = s;
        hp2[row] = 0u;           // max accumulator, non-negative domain
        hn2[row] = 0x7F800000u;  // +inf
    }
}

// ---------------------------------------------------------------------------
// Kernel 2: fused E @ E^T with hardest-pos/neg selection.
// Grid: 64 row-tiles x 8 column-splits = 512 blocks, 256 threads (4 waves).
// Block tile: 128 rows x 128 cols per j-tile, 8 j-tiles per block.
// Each wave: 64x64 via 4x4 grid of 16x16x32 bf16 MFMA.
// A tile (128x128 k) resident in LDS, stride 136 bf16 (68 words == 4 mod 32:
// balanced banks for b128 reads, 16B-aligned rows).
// B staged per 64-k chunk, stride 72 bf16 (36 words == 4 mod 32).
// ---------------------------------------------------------------------------
__global__ __launch_bounds__(256) void bhtl_main(
    const __hip_bfloat16* __restrict__ Ebf,
    const float* __restrict__ sq,
    const int* __restrict__ labels,
    unsigned* __restrict__ hp2,
    unsigned* __restrict__ hn2)
{
    __shared__ unsigned short A_s[128 * 136];
    __shared__ unsigned short B_s[128 * 72];

    const int tid = threadIdx.x;
    const int bid = blockIdx.x;
    const int rt  = bid >> 3;          // 0..63 row tile
    const int js  = bid & 7;           // 0..7 column split
    const int rowbase = rt * 128;
    const int jbase0  = js * 1024;

    const int lane = tid & 63;
    const int w    = tid >> 6;         // wave 0..3
    const int wr   = w >> 1;           // 0..1  row half
    const int wc   = w & 1;            // 0..1  col half
    const int q    = lane >> 4;        // quad 0..3
    const int ln   = lane & 15;

    // ---- stage A tile (128 rows x full K) ----
    #pragma unroll
    for (int it = 0; it < 8; ++it) {
        int idx = it * 256 + tid;          // 0..2047
        int row = idx >> 4;                // 0..127
        int kc  = idx & 15;                // 16B chunk along k
        uint4 v = *(const uint4*)(Ebf + (rowbase + row) * DIM + kc * 8);
        *(uint4*)(&A_s[row * 136 + kc * 8]) = v;
    }

    // ---- per-slot anchor metadata (16 rows per lane: m in 0..3, r in 0..3) ----
    float sqi[16];
    int   labi[16];
    #pragma unroll
    for (int m = 0; m < 4; ++m)
        #pragma unroll
        for (int r = 0; r < 4; ++r) {
            int row = rowbase + wr * 64 + m * 16 + q * 4 + r;
            sqi[m * 4 + r]  = sq[row];
            labi[m * 4 + r] = labels[row];
        }

    float maxpos[16], minneg[16];
    #pragma unroll
    for (int s = 0; s < 16; ++s) { maxpos[s] = -INFINITY; minneg[s] = INFINITY; }

    f32x4 acc[4][4];
    const f32x4 zero = {0.f, 0.f, 0.f, 0.f};

    for (int jt = 0; jt < 8; ++jt) {
        const int jbase = jbase0 + jt * 128;
        #pragma unroll
        for (int m = 0; m < 4; ++m)
            #pragma unroll
            for (int n = 0; n < 4; ++n) acc[m][n] = zero;

        for (int ch = 0; ch < 2; ++ch) {
            __syncthreads();   // protect B_s (and A_s on first pass)
            #pragma unroll
            for (int it = 0; it < 4; ++it) {
                int idx = it * 256 + tid;      // 0..1023
                int col = idx >> 3;            // 0..127
                int kc  = idx & 7;             // 16B chunk along 64-k window
                uint4 v = *(const uint4*)(Ebf + (jbase + col) * DIM + ch * 64 + kc * 8);
                *(uint4*)(&B_s[col * 72 + kc * 8]) = v;
            }
            __syncthreads();

            #pragma unroll
            for (int ks = 0; ks < 2; ++ks) {
                const int koff = ch * 64 + ks * 32;
                short8 af[4], bf[4];
                #pragma unroll
                for (int m = 0; m < 4; ++m)
                    af[m] = *(const short8*)(&A_s[(wr * 64 + m * 16 + ln) * 136 + koff + q * 8]);
                #pragma unroll
                for (int n = 0; n < 4; ++n)
                    bf[n] = *(const short8*)(&B_s[(wc * 64 + n * 16 + ln) * 72 + ks * 32 + q * 8]);
                #pragma unroll
                for (int m = 0; m < 4; ++m)
                    #pragma unroll
                    for (int n = 0; n < 4; ++n)
                        acc[m][n] = __builtin_amdgcn_mfma_f32_16x16x32_bf16(
                            af[m], bf[n], acc[m][n], 0, 0, 0);
            }
        }

        // ---- epilogue: val = sq_j - 2*dot ; select by label equality ----
        float sqj[4];
        int   labj[4];
        #pragma unroll
        for (int n = 0; n < 4; ++n) {
            int col = jbase + wc * 64 + n * 16 + ln;
            sqj[n]  = sq[col];
            labj[n] = labels[col];
        }
        #pragma unroll
        for (int m = 0; m < 4; ++m)
            #pragma unroll
            for (int n = 0; n < 4; ++n)
                #pragma unroll
                for (int r = 0; r < 4; ++r) {
                    float val  = fmaf(-2.0f, acc[m][n][r], sqj[n]);
                    bool same  = (labi[m * 4 + r] == labj[n]);
                    maxpos[m * 4 + r] = fmaxf(maxpos[m * 4 + r], same ? val : -INFINITY);
                    minneg[m * 4 + r] = fminf(minneg[m * 4 + r], same ? INFINITY : val);
                }
    }

    // ---- reduce across the 16 lanes sharing each row, then atomics ----
    #pragma unroll
    for (int s = 0; s < 16; ++s) {
        float mp = maxpos[s], mn = minneg[s];
        #pragma unroll
        for (int d = 1; d < 16; d <<= 1) {
            mp = fmaxf(mp, __shfl_xor(mp, d, 64));
            mn = fminf(mn, __shfl_xor(mn, d, 64));
        }
        if (ln == 0) {
            int m = s >> 2, r = s & 3;
            int row = rowbase + wr * 64 + m * 16 + q * 4 + r;
            // d2 = sq_i + (sq_j - 2 dot), clamped >= 0 so uint ordering == float ordering
            float hp2c = fmaxf(sqi[s] + mp, 0.0f);
            float hn2c = fmaxf(sqi[s] + mn, 0.0f);
            atomicMax(&hp2[row], __float_as_uint(hp2c));
            atomicMin(&hn2[row], __float_as_uint(hn2c));
        }
    }
}

// ---------------------------------------------------------------------------
// Kernel 3: per-anchor loss + mean. Single block, deterministic write of out.
// ---------------------------------------------------------------------------
__global__ __launch_bounds__(1024) void bhtl_final(
    const unsigned* __restrict__ hp2,
    const unsigned* __restrict__ hn2,
    float* __restrict__ out)
{
    __shared__ float red[16];
    float sum = 0.f;
    for (int i = threadIdx.x; i < BATCH; i += 1024) {
        float hp = sqrtf(__uint_as_float(hp2[i]));
        float hn = sqrtf(__uint_as_float(hn2[i]));
        sum += fmaxf(hp - hn + MARGIN, 0.f);
    }
    #pragma unroll
    for (int d = 1; d < 64; d <<= 1) sum += __shfl_xor(sum, d, 64);
    int wv = threadIdx.x >> 6;
    if ((threadIdx.x & 63) == 0) red[wv] = sum;
    __syncthreads();
    if (threadIdx.x < 64) {
        float v = (threadIdx.x < 16) ? red[threadIdx.x] : 0.f;
        #pragma unroll
        for (int d = 1; d < 16; d <<= 1) v += __shfl_xor(v, d, 64);
        if (threadIdx.x == 0) out[0] = v / (float)BATCH;
    }
}

// ---------------------------------------------------------------------------
extern "C" void kernel_launch(void* const* d_in, const int* in_sizes, int n_in,
                              void* d_out, int out_size, void* d_ws, size_t ws_size,
                              hipStream_t stream)
{
    const float* emb    = (const float*)d_in[0];
    const int*   labels = (const int*)d_in[1];
    float*       out    = (float*)d_out;

    char* ws = (char*)d_ws;
    __hip_bfloat16* Ebf = (__hip_bfloat16*)ws;                       // 2 MiB
    float*    sq  = (float*)   (ws + 2 * 1024 * 1024);               // 32 KiB
    unsigned* hp2 = (unsigned*)(ws + 2 * 1024 * 1024 + 32 * 1024);   // 32 KiB
    unsigned* hn2 = (unsigned*)(ws + 2 * 1024 * 1024 + 64 * 1024);   // 32 KiB

    bhtl_prep<<<BATCH, 64, 0, stream>>>(emb, Ebf, sq, hp2, hn2);
    bhtl_main<<<512, 256, 0, stream>>>(Ebf, sq, labels, hp2, hn2);
    bhtl_final<<<1, 1024, 0, stream>>>(hp2, hn2, out);
}

// Round 2
// 109.016 us; speedup vs baseline: 1.0298x; 1.0298x over previous
//
#include <hip/hip_runtime.h>
#include <hip/hip_bf16.h>
#include <cstdint>

#define BATCH 8192
#define DIM   128
#define MARGIN 1.0f

typedef __attribute__((ext_vector_type(8))) short short8;
typedef __attribute__((ext_vector_type(4))) float f32x4;

// ---------------------------------------------------------------------------
// Kernel 1: convert fp32 -> bf16, per-row squared norms (fp32-exact),
// init hp2 (max-accum) / hn2 (min-accum). One wave per row, 4 waves/block.
// ---------------------------------------------------------------------------
__global__ __launch_bounds__(256) void bhtl_prep(
    const float* __restrict__ emb,
    __hip_bfloat16* __restrict__ Ebf,
    float* __restrict__ sq,
    unsigned* __restrict__ hp2,
    unsigned* __restrict__ hn2)
{
    const int w   = threadIdx.x >> 6;
    const int l   = threadIdx.x & 63;
    const int row = blockIdx.x * 4 + w;
    const float2 e = ((const float2*)(emb + row * DIM))[l];
    __hip_bfloat162 h2;
    h2.x = __float2bfloat16(e.x);
    h2.y = __float2bfloat16(e.y);
    ((__hip_bfloat162*)(Ebf + row * DIM))[l] = h2;
    float s = e.x * e.x + e.y * e.y;
    #pragma unroll
    for (int d = 1; d < 64; d <<= 1) s += __shfl_xor(s, d, 64);
    if (l == 0) {
        sq[row]  = s;
        hp2[row] = 0u;           // max accumulator (non-negative domain)
        hn2[row] = 0x7F800000u;  // +inf
    }
}

// ---------------------------------------------------------------------------
// Kernel 2: fused E @ E^T + hardest-pos/neg selection. Barrier-free, no LDS.
// 512 blocks x 256 threads = 2048 waves, all resident at 2 waves/SIMD.
// Wave W: row band rb = W & 127 (64 rows), col split js = W >> 7 (512 cols).
// A fragments (64 rows x full K) live in 64 VGPRs for the whole kernel.
// Per 32-col step: 8 B-frag b128 loads (L1/L2-hit; block's 4 waves share js
// so the B sweep hits L1), 32 MFMAs (16x16x32 bf16), fused select epilogue.
// ---------------------------------------------------------------------------
__global__ __launch_bounds__(256, 2) void bhtl_main(
    const __hip_bfloat16* __restrict__ Ebf,
    const float* __restrict__ sq,
    const int* __restrict__ labels,
    unsigned* __restrict__ hp2,
    unsigned* __restrict__ hn2)
{
    const int w    = threadIdx.x >> 6;
    const int lane = threadIdx.x & 63;
    const int W    = blockIdx.x * 4 + w;   // 0..2047
    const int rb   = W & 127;              // row band (64 rows)
    const int js   = W >> 7;               // 0..15 column split (512 cols)
    const int rowbase = rb * 64;
    const int jbase0  = js * 512;
    const int q  = lane >> 4;              // 0..3
    const int ln = lane & 15;              // 0..15

    // ---- A fragments for the wave's 64 rows, full K=128 (held in regs) ----
    short8 af[4][4];
    #pragma unroll
    for (int m = 0; m < 4; ++m)
        #pragma unroll
        for (int kc = 0; kc < 4; ++kc)
            af[m][kc] = *(const short8*)(Ebf + (rowbase + m * 16 + ln) * DIM + kc * 32 + q * 8);

    // ---- anchor labels for this lane's 16 row slots (m*4 + r) ----
    int labi[16];
    #pragma unroll
    for (int m = 0; m < 4; ++m)
        #pragma unroll
        for (int r = 0; r < 4; ++r)
            labi[m * 4 + r] = labels[rowbase + m * 16 + q * 4 + r];

    float maxpos[16], minneg[16];
    #pragma unroll
    for (int s = 0; s < 16; ++s) { maxpos[s] = -INFINITY; minneg[s] = INFINITY; }

    const f32x4 zero = {0.f, 0.f, 0.f, 0.f};

    for (int jt = 0; jt < 16; ++jt) {       // 16 steps x 32 cols
        const int jb = jbase0 + jt * 32;

        short8 bf[2][4];
        #pragma unroll
        for (int n = 0; n < 2; ++n)
            #pragma unroll
            for (int kc = 0; kc < 4; ++kc)
                bf[n][kc] = *(const short8*)(Ebf + (jb + n * 16 + ln) * DIM + kc * 32 + q * 8);

        float sqj[2];
        int   labj[2];
        #pragma unroll
        for (int n = 0; n < 2; ++n) {
            int col = jb + n * 16 + ln;
            sqj[n]  = sq[col];
            labj[n] = labels[col];
        }

        f32x4 acc[4][2];
        #pragma unroll
        for (int m = 0; m < 4; ++m)
            #pragma unroll
            for (int n = 0; n < 2; ++n) acc[m][n] = zero;

        #pragma unroll
        for (int kc = 0; kc < 4; ++kc)
            #pragma unroll
            for (int m = 0; m < 4; ++m)
                #pragma unroll
                for (int n = 0; n < 2; ++n)
                    acc[m][n] = __builtin_amdgcn_mfma_f32_16x16x32_bf16(
                        af[m][kc], bf[n][kc], acc[m][n], 0, 0, 0);

        // ---- epilogue: val = sq_j - 2*dot ; select by label equality ----
        #pragma unroll
        for (int m = 0; m < 4; ++m)
            #pragma unroll
            for (int n = 0; n < 2; ++n)
                #pragma unroll
                for (int r = 0; r < 4; ++r) {
                    float val = fmaf(-2.0f, acc[m][n][r], sqj[n]);
                    bool same = (labi[m * 4 + r] == labj[n]);
                    maxpos[m * 4 + r] = fmaxf(maxpos[m * 4 + r], same ? val : -INFINITY);
                    minneg[m * 4 + r] = fminf(minneg[m * 4 + r], same ? INFINITY : val);
                }
    }

    // ---- reduce across the 16 ln-lanes sharing each row, then atomics ----
    #pragma unroll
    for (int s = 0; s < 16; ++s) {
        float mp = maxpos[s], mn = minneg[s];
        #pragma unroll
        for (int d = 1; d < 16; d <<= 1) {
            mp = fmaxf(mp, __shfl_xor(mp, d, 64));
            mn = fminf(mn, __shfl_xor(mn, d, 64));
        }
        if (ln == 0) {
            int row = rowbase + (s >> 2) * 16 + q * 4 + (s & 3);
            float sqi = sq[row];
            float hp2c = fmaxf(sqi + mp, 0.0f);   // clamp >=0: uint order == float order
            float hn2c = fmaxf(sqi + mn, 0.0f);
            atomicMax(&hp2[row], __float_as_uint(hp2c));
            atomicMin(&hn2[row], __float_as_uint(hn2c));
        }
    }
}

// ---------------------------------------------------------------------------
// Kernel 3: per-anchor loss + mean. Single block, deterministic output.
// ---------------------------------------------------------------------------
__global__ __launch_bounds__(1024) void bhtl_final(
    const unsigned* __restrict__ hp2,
    const unsigned* __restrict__ hn2,
    float* __restrict__ out)
{
    __shared__ float red[16];
    float sum = 0.f;
    for (int i = threadIdx.x; i < BATCH; i += 1024) {
        float hp = sqrtf(__uint_as_float(hp2[i]));
        float hn = sqrtf(__uint_as_float(hn2[i]));
        sum += fmaxf(hp - hn + MARGIN, 0.f);
    }
    #pragma unroll
    for (int d = 1; d < 64; d <<= 1) sum += __shfl_xor(sum, d, 64);
    int wv = threadIdx.x >> 6;
    if ((threadIdx.x & 63) == 0) red[wv] = sum;
    __syncthreads();
    if (threadIdx.x < 64) {
        float v = (threadIdx.x < 16) ? red[threadIdx.x] : 0.f;
        #pragma unroll
        for (int d = 1; d < 16; d <<= 1) v += __shfl_xor(v, d, 64);
        if (threadIdx.x == 0) out[0] = v / (float)BATCH;
    }
}

// ---------------------------------------------------------------------------
extern "C" void kernel_launch(void* const* d_in, const int* in_sizes, int n_in,
                              void* d_out, int out_size, void* d_ws, size_t ws_size,
                              hipStream_t stream)
{
    const float* emb    = (const float*)d_in[0];
    const int*   labels = (const int*)d_in[1];
    float*       out    = (float*)d_out;

    char* ws = (char*)d_ws;
    __hip_bfloat16* Ebf = (__hip_bfloat16*)ws;                       // 2 MiB
    float*    sq  = (float*)   (ws + 2 * 1024 * 1024);               // 32 KiB
    unsigned* hp2 = (unsigned*)(ws + 2 * 1024 * 1024 + 32 * 1024);   // 32 KiB
    unsigned* hn2 = (unsigned*)(ws + 2 * 1024 * 1024 + 64 * 1024);   // 32 KiB

    bhtl_prep<<<BATCH / 4, 256, 0, stream>>>(emb, Ebf, sq, hp2, hn2);
    bhtl_main<<<512, 256, 0, stream>>>(Ebf, sq, labels, hp2, hn2);
    bhtl_final<<<1, 1024, 0, stream>>>(hp2, hn2, out);
}